// Round 13
// baseline (58.822 us; speedup 1.0000x reference)
//
#include <hip/hip_runtime.h>

#define NB 4
#define NQ 256
#define NK 1024
#define ND 512
#define NH 128

typedef _Float16 half8_t __attribute__((ext_vector_type(8)));
typedef _Float16 half4_t __attribute__((ext_vector_type(4)));
typedef _Float16 half2_t __attribute__((ext_vector_type(2)));
typedef float f32x4_t __attribute__((ext_vector_type(4)));

#define TANH_C 2.8853900817779268f  // 2*log2(e): tanh(x)=1-2/(exp2(C*x)+1)

// ---------------------------------------------------------------------------
// Kernel 1 (proj + vT, fused; independent roles per block) -- R12, unchanged.
// ---------------------------------------------------------------------------
__global__ __launch_bounds__(256) void projvt_kernel(
    const float* __restrict__ queries, const float* __restrict__ keys,
    const float* __restrict__ Wq, const float* __restrict__ Wk,
    const float* __restrict__ values, float* __restrict__ EQ,
    float* __restrict__ EKT, _Float16* __restrict__ vT) {
  __shared__ __align__(16) char smem[33280];
  const int bid = blockIdx.x;
  const int t = threadIdx.x;

  if (bid < 320) {  // ---------------- projection ----------------
    _Float16* wlds = (_Float16*)smem;  // [32][520] halfs, swizzled
    const int hgrp = bid & 3;
    const int rblk = bid >> 2;         // 0..79
    const int row0_blk = rblk * 64;
    const bool is_q = row0_blk < NB * NQ;
    const float* X = is_q ? queries : (keys - (size_t)NB * NQ * ND);
    const float* W = is_q ? Wq : Wk;
    const int h0 = hgrp * 32;

    {  // stage W[*][h0..h0+32) -> wlds[j][d ^ ((j&7)<<3)]
      const int j = t & 31;
      const int dg = t >> 5;  // 0..7
      const int jx = (j & 7) << 3;
      #pragma unroll 8
      for (int pass = 0; pass < 64; ++pass) {
        const int d = pass * 8 + dg;
        wlds[j * 520 + (d ^ jx)] = (_Float16)W[(size_t)d * NH + h0 + j];
      }
    }
    __syncthreads();

    const int w = t >> 6;
    const int l = t & 63;
    const int row0 = row0_blk + w * 16;
    const float* xrow = X + (size_t)(row0 + (l & 15)) * ND + (l >> 4) * 8;
    const int hA = l & 15;
    const int xorA = (hA & 7) << 3;

    f32x4_t acc0 = {0.f, 0.f, 0.f, 0.f};
    f32x4_t acc1 = {0.f, 0.f, 0.f, 0.f};
    #pragma unroll 4
    for (int d = 0; d < ND; d += 32) {
      const float4 x0 = *(const float4*)(xrow + d);
      const float4 x1 = *(const float4*)(xrow + d + 4);
      half8_t a;
      a[0] = (_Float16)x0.x; a[1] = (_Float16)x0.y;
      a[2] = (_Float16)x0.z; a[3] = (_Float16)x0.w;
      a[4] = (_Float16)x1.x; a[5] = (_Float16)x1.y;
      a[6] = (_Float16)x1.z; a[7] = (_Float16)x1.w;
      const int dfrag = d + (l >> 4) * 8;
      const half8_t b0 =
          *(const half8_t*)&wlds[hA * 520 + (dfrag ^ xorA)];
      const half8_t b1 =
          *(const half8_t*)&wlds[(16 + hA) * 520 + (dfrag ^ xorA)];
      acc0 = __builtin_amdgcn_mfma_f32_16x16x32_f16(a, b0, acc0, 0, 0, 0);
      acc1 = __builtin_amdgcn_mfma_f32_16x16x32_f16(a, b1, acc1, 0, 0, 0);
    }
    const int mrow = row0 + (l >> 4) * 4;
    const int hcol = h0 + hA;
    if (is_q) {
      #pragma unroll
      for (int r = 0; r < 4; ++r) {
        EQ[(size_t)(mrow + r) * NH + hcol] = __builtin_exp2f(TANH_C * acc0[r]);
        EQ[(size_t)(mrow + r) * NH + hcol + 16] =
            __builtin_exp2f(TANH_C * acc1[r]);
      }
    } else {
      const int rowk = mrow - NB * NQ;  // 0..4095
      const int bb = rowk >> 10;
      const int kk = rowk & 1023;
      float4 v0, v1;
      v0.x = __builtin_exp2f(TANH_C * acc0[0]);
      v0.y = __builtin_exp2f(TANH_C * acc0[1]);
      v0.z = __builtin_exp2f(TANH_C * acc0[2]);
      v0.w = __builtin_exp2f(TANH_C * acc0[3]);
      v1.x = __builtin_exp2f(TANH_C * acc1[0]);
      v1.y = __builtin_exp2f(TANH_C * acc1[1]);
      v1.z = __builtin_exp2f(TANH_C * acc1[2]);
      v1.w = __builtin_exp2f(TANH_C * acc1[3]);
      *(float4*)(EKT + ((size_t)(bb * NH + hcol)) * NK + kk) = v0;
      *(float4*)(EKT + ((size_t)(bb * NH + hcol + 16)) * NK + kk) = v1;
    }
    return;
  }

  // ---------------- values transpose (64x64 tile) ----------------
  const int vb = bid - 320;  // 0..511
  float(*tile)[65] = (float(*)[65])smem;
  const int dt = vb & 7;
  const int kt = (vb >> 3) & 15;
  const int b = vb >> 7;
  const int k0 = kt * 64, d0 = dt * 64;
  {
    const int kl = t >> 4, dl4 = (t & 15) * 4;
    #pragma unroll
    for (int i = 0; i < 4; ++i) {
      const float4 v = *(const float4*)(
          values + ((size_t)(b * NK + k0 + kl + i * 16)) * ND + d0 + dl4);
      tile[dl4 + 0][kl + i * 16] = v.x;
      tile[dl4 + 1][kl + i * 16] = v.y;
      tile[dl4 + 2][kl + i * 16] = v.z;
      tile[dl4 + 3][kl + i * 16] = v.w;
    }
  }
  __syncthreads();
  const int dr = t >> 2, kc = (t & 3) * 16;
  half8_t h0v, h1v;
  #pragma unroll
  for (int ii = 0; ii < 8; ++ii) {
    h0v[ii] = (_Float16)tile[dr][kc + ii];
    h1v[ii] = (_Float16)tile[dr][kc + 8 + ii];
  }
  _Float16* dst = vT + ((size_t)(b * ND + d0 + dr)) * NK + k0 + kc;
  *(half8_t*)dst = h0v;
  *(half8_t*)(dst + 8) = h1v;
}

// ---------------------------------------------------------------------------
// Kernel 2: fused scores + softmax -> fp16 attn.
// R11 structure (grid 512, 8 waves, wave = 128k x 2q) but UNPAIRED rcp math:
// per (acc,h): d = fma(eq, ek, 1); acc = fma(wv, rcp(d), acc)  -- 2 VALU +
// 1 trans, vs paired's 3 VALU + 0.5 trans. Scores is VALU-bound (R10->R11
// traffic halving was null), and trans/VALU overlap on separate pipes, so
// unpaired is ~1.4x on the critical pipe.
// ---------------------------------------------------------------------------
__global__ __launch_bounds__(512, 4) void scores_softmax_kernel(
    const float* __restrict__ EQ, const float* __restrict__ EKT,
    const float* __restrict__ wv, const int* __restrict__ vlen,
    _Float16* __restrict__ attn_h) {
  __shared__ float4 eqwv2[2][64];  // [q][h/2] = {eq_h, wv_h, eq_h+1, wv_h+1}
  __shared__ float red[2][2][8];
  const int bid = blockIdx.x;
  const int b = bid >> 7;
  const int q0 = (bid & 127) * 2;
  const int t = threadIdx.x;
  const int w = t >> 6;
  const int l = t & 63;
  const int vl = vlen[b];

  if (t < 128) {
    const int qq = t >> 6, i = t & 63;
    const float* eqrow = EQ + (size_t)(b * NQ + q0 + qq) * NH;
    eqwv2[qq][i] = make_float4(eqrow[2 * i], wv[2 * i],
                               eqrow[2 * i + 1], wv[2 * i + 1]);
  }
  __syncthreads();

  float Wsum;
  {
    const float4 a = eqwv2[0][l];
    Wsum = a.y + a.w;
    #pragma unroll
    for (int off = 32; off; off >>= 1) Wsum += __shfl_xor(Wsum, off);
  }

  const int k0 = w * 128;
  float a00 = 0.f, a01 = 0.f, a10 = 0.f, a11 = 0.f;  // [q][k]
  if (k0 < vl) {
    const float* ekb = EKT + (size_t)(b * NH) * NK + k0 + l * 2;
    #pragma unroll 4
    for (int hh = 0; hh < 64; ++hh) {
      const float4 qw0 = eqwv2[0][hh];  // {eqA, wvA, eqB, wvB} for q0
      const float4 qw1 = eqwv2[1][hh];  // ... for q1
      const float2 ea = *(const float2*)(ekb + (size_t)(2 * hh) * NK);
      const float2 eb = *(const float2*)(ekb + (size_t)(2 * hh + 1) * NK);
      // h = 2hh (ea), unpaired rcp per (q,k):
      a00 = fmaf(qw0.y, __builtin_amdgcn_rcpf(fmaf(qw0.x, ea.x, 1.f)), a00);
      a01 = fmaf(qw0.y, __builtin_amdgcn_rcpf(fmaf(qw0.x, ea.y, 1.f)), a01);
      a10 = fmaf(qw1.y, __builtin_amdgcn_rcpf(fmaf(qw1.x, ea.x, 1.f)), a10);
      a11 = fmaf(qw1.y, __builtin_amdgcn_rcpf(fmaf(qw1.x, ea.y, 1.f)), a11);
      // h = 2hh+1 (eb):
      a00 = fmaf(qw0.w, __builtin_amdgcn_rcpf(fmaf(qw0.z, eb.x, 1.f)), a00);
      a01 = fmaf(qw0.w, __builtin_amdgcn_rcpf(fmaf(qw0.z, eb.y, 1.f)), a01);
      a10 = fmaf(qw1.w, __builtin_amdgcn_rcpf(fmaf(qw1.z, eb.x, 1.f)), a10);
      a11 = fmaf(qw1.w, __builtin_amdgcn_rcpf(fmaf(qw1.z, eb.y, 1.f)), a11);
    }
  }

  const int kA = k0 + l * 2, kB = kA + 1;
  float s00 = (kA < vl) ? (Wsum - 2.f * a00) : 0.f;
  float s01 = (kB < vl) ? (Wsum - 2.f * a01) : 0.f;
  float s10 = (kA < vl) ? (Wsum - 2.f * a10) : 0.f;
  float s11 = (kB < vl) ? (Wsum - 2.f * a11) : 0.f;

  float m0 = fmaxf(s00, s01), m1 = fmaxf(s10, s11);
  #pragma unroll
  for (int off = 32; off; off >>= 1) {
    m0 = fmaxf(m0, __shfl_xor(m0, off));
    m1 = fmaxf(m1, __shfl_xor(m1, off));
  }
  if (l == 0) { red[0][0][w] = m0; red[0][1][w] = m1; }
  __syncthreads();
  m0 = red[0][0][0]; m1 = red[0][1][0];
  #pragma unroll
  for (int i = 1; i < 8; ++i) {
    m0 = fmaxf(m0, red[0][0][i]);
    m1 = fmaxf(m1, red[0][1][i]);
  }
  const float ce = 1.4426950408889634f;
  s00 = __builtin_exp2f(ce * (s00 - m0));
  s01 = __builtin_exp2f(ce * (s01 - m0));
  s10 = __builtin_exp2f(ce * (s10 - m1));
  s11 = __builtin_exp2f(ce * (s11 - m1));
  float sum0 = s00 + s01, sum1 = s10 + s11;
  #pragma unroll
  for (int off = 32; off; off >>= 1) {
    sum0 += __shfl_xor(sum0, off);
    sum1 += __shfl_xor(sum1, off);
  }
  if (l == 0) { red[1][0][w] = sum0; red[1][1][w] = sum1; }
  __syncthreads();
  float Z0 = 0.f, Z1 = 0.f;
  #pragma unroll
  for (int i = 0; i < 8; ++i) { Z0 += red[1][0][i]; Z1 += red[1][1][i]; }
  const float inv0 = 1.0f / Z0, inv1 = 1.0f / Z1;
  half2_t h0, h1;
  h0[0] = (_Float16)(s00 * inv0); h0[1] = (_Float16)(s01 * inv0);
  h1[0] = (_Float16)(s10 * inv1); h1[1] = (_Float16)(s11 * inv1);
  *(half2_t*)(attn_h + (size_t)(b * NQ + q0) * NK + kA) = h0;
  *(half2_t*)(attn_h + (size_t)(b * NQ + q0 + 1) * NK + kA) = h1;
}

// ---------------------------------------------------------------------------
// Kernel 3: PV via MFMA fp16, full-K per block, plain stores (R11, unchanged).
// ---------------------------------------------------------------------------
__global__ __launch_bounds__(256) void pv_mfma_kernel(
    const _Float16* __restrict__ attn_h, const _Float16* __restrict__ vT,
    float* __restrict__ out) {
  const int bid = blockIdx.x;
  const int dt = bid & 7;
  const int qt = (bid >> 3) & 15;
  const int b  = bid >> 7;
  const int w = threadIdx.x >> 6;
  const int l = threadIdx.x & 63;
  const int q_lo = qt * 16;
  const int d_lo = dt * 64 + w * 16;

  const _Float16* arow =
      attn_h + ((size_t)(b * NQ + q_lo + (l & 15))) * NK + (l >> 4) * 8;
  const _Float16* brow =
      vT + ((size_t)(b * ND + d_lo + (l & 15))) * NK + (l >> 4) * 8;

  f32x4_t acc = {0.f, 0.f, 0.f, 0.f};
  #pragma unroll 8
  for (int ks = 0; ks < NK; ks += 32) {
    const half8_t a = *(const half8_t*)(arow + ks);
    const half8_t bb = *(const half8_t*)(brow + ks);
    acc = __builtin_amdgcn_mfma_f32_16x16x32_f16(a, bb, acc, 0, 0, 0);
  }
  const int mrow = q_lo + (l >> 4) * 4;
  const int dcol = d_lo + (l & 15);
  #pragma unroll
  for (int r = 0; r < 4; ++r)
    out[(size_t)(b * NQ + mrow + r) * ND + dcol] = acc[r];
}

// ---------------------------------------------------------------------------
extern "C" void kernel_launch(void* const* d_in, const int* in_sizes, int n_in,
                              void* d_out, int out_size, void* d_ws, size_t ws_size,
                              hipStream_t stream) {
  const float* queries = (const float*)d_in[0];
  const float* keys    = (const float*)d_in[1];
  const float* values  = (const float*)d_in[2];
  const float* Wq      = (const float*)d_in[3];
  const float* Wk      = (const float*)d_in[4];
  const float* wv      = (const float*)d_in[5];
  const int*   vlen    = (const int*)d_in[6];
  float* out = (float*)d_out;

  // ws layout (bytes; total ~8.6 MB; d_ws is ~256 MB):
  char* ws = (char*)d_ws;
  float*     EQ     = (float*)(ws);                    // 512 KB (row-major)
  float*     EKT    = (float*)(ws + (512 << 10));      // 2 MB   (transposed)
  _Float16*  attn_h = (_Float16*)(ws + (2560 << 10));  // 2 MB
  _Float16*  vT     = (_Float16*)(ws + (4608 << 10));  // 4 MB

  projvt_kernel<<<832, 256, 0, stream>>>(queries, keys, Wq, Wk, values,
                                         EQ, EKT, vT);
  scores_softmax_kernel<<<NB * (NQ / 2), 512, 0, stream>>>(EQ, EKT, wv, vlen,
                                                           attn_h);
  pv_mfma_kernel<<<NB * 16 * 8, 256, 0, stream>>>(attn_h, vT, out);
}

// Round 14
// 53.961 us; speedup vs baseline: 1.0901x; 1.0901x over previous
//
#include <hip/hip_runtime.h>

#define NB 4
#define NQ 256
#define NK 1024
#define ND 512
#define NH 128

typedef _Float16 half8_t __attribute__((ext_vector_type(8)));
typedef _Float16 half4_t __attribute__((ext_vector_type(4)));
typedef _Float16 half2_t __attribute__((ext_vector_type(2)));
typedef float f32x4_t __attribute__((ext_vector_type(4)));

#define TANH_C 2.8853900817779268f  // 2*log2(e): tanh(x)=1-2/(exp2(C*x)+1)

// ---------------------------------------------------------------------------
// REVERT to R12 (best measured: 54.2 us). R13's unpaired-rcp experiment
// regressed (+4.6 us): the trans pipe, not VALU, was the tighter constraint
// in scores -- paired rcp (0.5 rcp per (q,k,h)) is the pipe-balance optimum.
// ---------------------------------------------------------------------------

// ---------------------------------------------------------------------------
// Kernel 1 (proj + vT, fused; independent roles per block):
//  blocks 0..319 : projection via MFMA fp16, W staged in LDS (XOR-swizzled).
//  blocks 320..831: values (B,K,D) fp32 -> vT (B,D,K) fp16.
// ---------------------------------------------------------------------------
__global__ __launch_bounds__(256) void projvt_kernel(
    const float* __restrict__ queries, const float* __restrict__ keys,
    const float* __restrict__ Wq, const float* __restrict__ Wk,
    const float* __restrict__ values, float* __restrict__ EQ,
    float* __restrict__ EKT, _Float16* __restrict__ vT) {
  __shared__ __align__(16) char smem[33280];
  const int bid = blockIdx.x;
  const int t = threadIdx.x;

  if (bid < 320) {  // ---------------- projection ----------------
    _Float16* wlds = (_Float16*)smem;  // [32][520] halfs, swizzled
    const int hgrp = bid & 3;
    const int rblk = bid >> 2;         // 0..79
    const int row0_blk = rblk * 64;
    const bool is_q = row0_blk < NB * NQ;
    const float* X = is_q ? queries : (keys - (size_t)NB * NQ * ND);
    const float* W = is_q ? Wq : Wk;
    const int h0 = hgrp * 32;

    {  // stage W[*][h0..h0+32) -> wlds[j][d ^ ((j&7)<<3)]
      const int j = t & 31;
      const int dg = t >> 5;  // 0..7
      const int jx = (j & 7) << 3;
      #pragma unroll 8
      for (int pass = 0; pass < 64; ++pass) {
        const int d = pass * 8 + dg;
        wlds[j * 520 + (d ^ jx)] = (_Float16)W[(size_t)d * NH + h0 + j];
      }
    }
    __syncthreads();

    const int w = t >> 6;
    const int l = t & 63;
    const int row0 = row0_blk + w * 16;
    const float* xrow = X + (size_t)(row0 + (l & 15)) * ND + (l >> 4) * 8;
    const int hA = l & 15;
    const int xorA = (hA & 7) << 3;

    f32x4_t acc0 = {0.f, 0.f, 0.f, 0.f};
    f32x4_t acc1 = {0.f, 0.f, 0.f, 0.f};
    #pragma unroll 4
    for (int d = 0; d < ND; d += 32) {
      const float4 x0 = *(const float4*)(xrow + d);
      const float4 x1 = *(const float4*)(xrow + d + 4);
      half8_t a;
      a[0] = (_Float16)x0.x; a[1] = (_Float16)x0.y;
      a[2] = (_Float16)x0.z; a[3] = (_Float16)x0.w;
      a[4] = (_Float16)x1.x; a[5] = (_Float16)x1.y;
      a[6] = (_Float16)x1.z; a[7] = (_Float16)x1.w;
      const int dfrag = d + (l >> 4) * 8;
      const half8_t b0 =
          *(const half8_t*)&wlds[hA * 520 + (dfrag ^ xorA)];
      const half8_t b1 =
          *(const half8_t*)&wlds[(16 + hA) * 520 + (dfrag ^ xorA)];
      acc0 = __builtin_amdgcn_mfma_f32_16x16x32_f16(a, b0, acc0, 0, 0, 0);
      acc1 = __builtin_amdgcn_mfma_f32_16x16x32_f16(a, b1, acc1, 0, 0, 0);
    }
    const int mrow = row0 + (l >> 4) * 4;
    const int hcol = h0 + hA;
    if (is_q) {
      #pragma unroll
      for (int r = 0; r < 4; ++r) {
        EQ[(size_t)(mrow + r) * NH + hcol] = __builtin_exp2f(TANH_C * acc0[r]);
        EQ[(size_t)(mrow + r) * NH + hcol + 16] =
            __builtin_exp2f(TANH_C * acc1[r]);
      }
    } else {
      const int rowk = mrow - NB * NQ;  // 0..4095
      const int bb = rowk >> 10;
      const int kk = rowk & 1023;
      float4 v0, v1;
      v0.x = __builtin_exp2f(TANH_C * acc0[0]);
      v0.y = __builtin_exp2f(TANH_C * acc0[1]);
      v0.z = __builtin_exp2f(TANH_C * acc0[2]);
      v0.w = __builtin_exp2f(TANH_C * acc0[3]);
      v1.x = __builtin_exp2f(TANH_C * acc1[0]);
      v1.y = __builtin_exp2f(TANH_C * acc1[1]);
      v1.z = __builtin_exp2f(TANH_C * acc1[2]);
      v1.w = __builtin_exp2f(TANH_C * acc1[3]);
      *(float4*)(EKT + ((size_t)(bb * NH + hcol)) * NK + kk) = v0;
      *(float4*)(EKT + ((size_t)(bb * NH + hcol + 16)) * NK + kk) = v1;
    }
    return;
  }

  // ---------------- values transpose (64x64 tile) ----------------
  const int vb = bid - 320;  // 0..511
  float(*tile)[65] = (float(*)[65])smem;
  const int dt = vb & 7;
  const int kt = (vb >> 3) & 15;
  const int b = vb >> 7;
  const int k0 = kt * 64, d0 = dt * 64;
  {
    const int kl = t >> 4, dl4 = (t & 15) * 4;
    #pragma unroll
    for (int i = 0; i < 4; ++i) {
      const float4 v = *(const float4*)(
          values + ((size_t)(b * NK + k0 + kl + i * 16)) * ND + d0 + dl4);
      tile[dl4 + 0][kl + i * 16] = v.x;
      tile[dl4 + 1][kl + i * 16] = v.y;
      tile[dl4 + 2][kl + i * 16] = v.z;
      tile[dl4 + 3][kl + i * 16] = v.w;
    }
  }
  __syncthreads();
  const int dr = t >> 2, kc = (t & 3) * 16;
  half8_t h0v, h1v;
  #pragma unroll
  for (int ii = 0; ii < 8; ++ii) {
    h0v[ii] = (_Float16)tile[dr][kc + ii];
    h1v[ii] = (_Float16)tile[dr][kc + 8 + ii];
  }
  _Float16* dst = vT + ((size_t)(b * ND + d0 + dr)) * NK + k0 + kc;
  *(half8_t*)dst = h0v;
  *(half8_t*)(dst + 8) = h1v;
}

// ---------------------------------------------------------------------------
// Kernel 2: fused scores + softmax -> fp16 attn (R12: paired rcp).
// Grid 512 = (b, q-pair); 8 waves; wave = 128-k chunk covering both q rows.
// Paired rcp: w1/d1 + w2/d2 = (w1*d2 + w2*d1) * rcp(d1*d2).
// ---------------------------------------------------------------------------
__global__ __launch_bounds__(512, 4) void scores_softmax_kernel(
    const float* __restrict__ EQ, const float* __restrict__ EKT,
    const float* __restrict__ wv, const int* __restrict__ vlen,
    _Float16* __restrict__ attn_h) {
  __shared__ float4 eqwv2[2][64];  // [q][h/2] = {eq_h, wv_h, eq_h+1, wv_h+1}
  __shared__ float red[2][2][8];
  const int bid = blockIdx.x;
  const int b = bid >> 7;
  const int q0 = (bid & 127) * 2;
  const int t = threadIdx.x;
  const int w = t >> 6;
  const int l = t & 63;
  const int vl = vlen[b];

  if (t < 128) {
    const int qq = t >> 6, i = t & 63;
    const float* eqrow = EQ + (size_t)(b * NQ + q0 + qq) * NH;
    eqwv2[qq][i] = make_float4(eqrow[2 * i], wv[2 * i],
                               eqrow[2 * i + 1], wv[2 * i + 1]);
  }
  __syncthreads();

  float Wsum;
  {
    const float4 a = eqwv2[0][l];
    Wsum = a.y + a.w;
    #pragma unroll
    for (int off = 32; off; off >>= 1) Wsum += __shfl_xor(Wsum, off);
  }

  const int k0 = w * 128;
  float a00 = 0.f, a01 = 0.f, a10 = 0.f, a11 = 0.f;  // [q][k]
  if (k0 < vl) {
    const float* ekb = EKT + (size_t)(b * NH) * NK + k0 + l * 2;
    #pragma unroll 4
    for (int hh = 0; hh < 64; ++hh) {
      const float4 qw0 = eqwv2[0][hh];  // {eqA, wvA, eqB, wvB} for q0
      const float4 qw1 = eqwv2[1][hh];  // ... for q1
      const float2 ea = *(const float2*)(ekb + (size_t)(2 * hh) * NK);
      const float2 eb = *(const float2*)(ekb + (size_t)(2 * hh + 1) * NK);
      {
        const float da = fmaf(qw0.x, ea.x, 1.f), db = fmaf(qw0.z, eb.x, 1.f);
        a00 = fmaf(fmaf(qw0.y, db, qw0.w * da),
                   __builtin_amdgcn_rcpf(da * db), a00);
      }
      {
        const float da = fmaf(qw0.x, ea.y, 1.f), db = fmaf(qw0.z, eb.y, 1.f);
        a01 = fmaf(fmaf(qw0.y, db, qw0.w * da),
                   __builtin_amdgcn_rcpf(da * db), a01);
      }
      {
        const float da = fmaf(qw1.x, ea.x, 1.f), db = fmaf(qw1.z, eb.x, 1.f);
        a10 = fmaf(fmaf(qw1.y, db, qw1.w * da),
                   __builtin_amdgcn_rcpf(da * db), a10);
      }
      {
        const float da = fmaf(qw1.x, ea.y, 1.f), db = fmaf(qw1.z, eb.y, 1.f);
        a11 = fmaf(fmaf(qw1.y, db, qw1.w * da),
                   __builtin_amdgcn_rcpf(da * db), a11);
      }
    }
  }

  const int kA = k0 + l * 2, kB = kA + 1;
  float s00 = (kA < vl) ? (Wsum - 2.f * a00) : 0.f;
  float s01 = (kB < vl) ? (Wsum - 2.f * a01) : 0.f;
  float s10 = (kA < vl) ? (Wsum - 2.f * a10) : 0.f;
  float s11 = (kB < vl) ? (Wsum - 2.f * a11) : 0.f;

  float m0 = fmaxf(s00, s01), m1 = fmaxf(s10, s11);
  #pragma unroll
  for (int off = 32; off; off >>= 1) {
    m0 = fmaxf(m0, __shfl_xor(m0, off));
    m1 = fmaxf(m1, __shfl_xor(m1, off));
  }
  if (l == 0) { red[0][0][w] = m0; red[0][1][w] = m1; }
  __syncthreads();
  m0 = red[0][0][0]; m1 = red[0][1][0];
  #pragma unroll
  for (int i = 1; i < 8; ++i) {
    m0 = fmaxf(m0, red[0][0][i]);
    m1 = fmaxf(m1, red[0][1][i]);
  }
  const float ce = 1.4426950408889634f;
  s00 = __builtin_exp2f(ce * (s00 - m0));
  s01 = __builtin_exp2f(ce * (s01 - m0));
  s10 = __builtin_exp2f(ce * (s10 - m1));
  s11 = __builtin_exp2f(ce * (s11 - m1));
  float sum0 = s00 + s01, sum1 = s10 + s11;
  #pragma unroll
  for (int off = 32; off; off >>= 1) {
    sum0 += __shfl_xor(sum0, off);
    sum1 += __shfl_xor(sum1, off);
  }
  if (l == 0) { red[1][0][w] = sum0; red[1][1][w] = sum1; }
  __syncthreads();
  float Z0 = 0.f, Z1 = 0.f;
  #pragma unroll
  for (int i = 0; i < 8; ++i) { Z0 += red[1][0][i]; Z1 += red[1][1][i]; }
  const float inv0 = 1.0f / Z0, inv1 = 1.0f / Z1;
  half2_t h0, h1;
  h0[0] = (_Float16)(s00 * inv0); h0[1] = (_Float16)(s01 * inv0);
  h1[0] = (_Float16)(s10 * inv1); h1[1] = (_Float16)(s11 * inv1);
  *(half2_t*)(attn_h + (size_t)(b * NQ + q0) * NK + kA) = h0;
  *(half2_t*)(attn_h + (size_t)(b * NQ + q0 + 1) * NK + kA) = h1;
}

// ---------------------------------------------------------------------------
// Kernel 3: PV via MFMA fp16, full-K per block, plain stores.
// ---------------------------------------------------------------------------
__global__ __launch_bounds__(256) void pv_mfma_kernel(
    const _Float16* __restrict__ attn_h, const _Float16* __restrict__ vT,
    float* __restrict__ out) {
  const int bid = blockIdx.x;
  const int dt = bid & 7;
  const int qt = (bid >> 3) & 15;
  const int b  = bid >> 7;
  const int w = threadIdx.x >> 6;
  const int l = threadIdx.x & 63;
  const int q_lo = qt * 16;
  const int d_lo = dt * 64 + w * 16;

  const _Float16* arow =
      attn_h + ((size_t)(b * NQ + q_lo + (l & 15))) * NK + (l >> 4) * 8;
  const _Float16* brow =
      vT + ((size_t)(b * ND + d_lo + (l & 15))) * NK + (l >> 4) * 8;

  f32x4_t acc = {0.f, 0.f, 0.f, 0.f};
  #pragma unroll 8
  for (int ks = 0; ks < NK; ks += 32) {
    const half8_t a = *(const half8_t*)(arow + ks);
    const half8_t bb = *(const half8_t*)(brow + ks);
    acc = __builtin_amdgcn_mfma_f32_16x16x32_f16(a, bb, acc, 0, 0, 0);
  }
  const int mrow = q_lo + (l >> 4) * 4;
  const int dcol = d_lo + (l & 15);
  #pragma unroll
  for (int r = 0; r < 4; ++r)
    out[(size_t)(b * NQ + mrow + r) * ND + dcol] = acc[r];
}

// ---------------------------------------------------------------------------
extern "C" void kernel_launch(void* const* d_in, const int* in_sizes, int n_in,
                              void* d_out, int out_size, void* d_ws, size_t ws_size,
                              hipStream_t stream) {
  const float* queries = (const float*)d_in[0];
  const float* keys    = (const float*)d_in[1];
  const float* values  = (const float*)d_in[2];
  const float* Wq      = (const float*)d_in[3];
  const float* Wk      = (const float*)d_in[4];
  const float* wv      = (const float*)d_in[5];
  const int*   vlen    = (const int*)d_in[6];
  float* out = (float*)d_out;

  // ws layout (bytes; total ~8.6 MB; d_ws is ~256 MB):
  char* ws = (char*)d_ws;
  float*     EQ     = (float*)(ws);                    // 512 KB (row-major)
  float*     EKT    = (float*)(ws + (512 << 10));      // 2 MB   (transposed)
  _Float16*  attn_h = (_Float16*)(ws + (2560 << 10));  // 2 MB
  _Float16*  vT     = (_Float16*)(ws + (4608 << 10));  // 4 MB

  projvt_kernel<<<832, 256, 0, stream>>>(queries, keys, Wq, Wk, values,
                                         EQ, EKT, vT);
  scores_softmax_kernel<<<NB * (NQ / 2), 512, 0, stream>>>(EQ, EKT, wv, vlen,
                                                           attn_h);
  pv_mfma_kernel<<<NB * 16 * 8, 256, 0, stream>>>(attn_h, vT, out);
}